// Round 2
// baseline (2295.828 us; speedup 1.0000x reference)
//
#include <hip/hip_runtime.h>

typedef _Float16 f16;
typedef _Float16 f16x8 __attribute__((ext_vector_type(8)));
typedef _Float16 f16x4 __attribute__((ext_vector_type(4)));
typedef float f32x4 __attribute__((ext_vector_type(4)));

#define GLDS(gp, lp) __builtin_amdgcn_global_load_lds( \
    (__attribute__((address_space(1))) void*)(gp),     \
    (__attribute__((address_space(3))) void*)(lp), 16, 0, 0)

// ---------------------------------------------------------------------------
// Dtype probe: scales真 values lie in [0.01, 0.06]. Check the first 64
// elements under f16 / bf16 / f32 interpretation; the wrong interpretations
// fall out of range for every storage scenario (incl. f16->f32 upcast where
// the low half is +-0.0). Writes mode: 0=f16, 1=bf16, 2=f32. Graph-safe.
// ---------------------------------------------------------------------------
__global__ void detect_kernel(const unsigned short* __restrict__ sc, int* __restrict__ mode)
{
    if (threadIdx.x != 0 || blockIdx.x != 0) return;
    bool ok16 = true, okbf = true;
    for (int i = 0; i < 64; i++) {
        const unsigned short b = sc[i];
        union { unsigned short u; f16 h; } ch; ch.u = b;
        const float fv = (float)ch.h;
        if (!(fv > 0.008f && fv < 0.062f)) ok16 = false;
        union { unsigned int u; float f; } cb; cb.u = ((unsigned int)b) << 16;
        if (!(cb.f > 0.008f && cb.f < 0.062f)) okbf = false;
    }
    *mode = ok16 ? 0 : (okbf ? 1 : 2);
}

__device__ __forceinline__ float load_half_like(const void* p, int i, int mode)
{
    if (mode == 0) return (float)((const f16*)p)[i];
    if (mode == 1) {
        union { unsigned int u; float f; } c;
        c.u = ((unsigned int)((const unsigned short*)p)[i]) << 16;
        return c.f;
    }
    return ((const float*)p)[i];
}

// ---------------------------------------------------------------------------
// Prep: dequant 4-bit -> f16 weights (code part exactly in f16, x f32 scale),
// lora_A -> f16, lora_B*0.125 -> f16, x -> f16, biases -> f32.
// Block ranges: dequant 3840 | A16 480 | B16 480 | x16 8192 | bias 15 = 13007
// ---------------------------------------------------------------------------
__global__ void prep_kernel(const float* __restrict__ x, const int* __restrict__ qw,
                            const void* __restrict__ scales, const void* __restrict__ biases,
                            const float* __restrict__ lA, const float* __restrict__ lB,
                            const int* __restrict__ modep,
                            f16* __restrict__ Wdq, f16* __restrict__ A16,
                            f16* __restrict__ B16, f16* __restrict__ x16,
                            float* __restrict__ bias32)
{
    const int bid = blockIdx.x, tid = threadIdx.x;
    if (bid < 3840) {
        const int md = *modep;
        const int g = bid * 256 + tid;                 // group id; scale idx == g
        const float s = load_half_like(scales, g, md);
        const int4* qp = (const int4*)(qw + (size_t)g * 16);
        f16x8 w0, w1;
        #pragma unroll
        for (int v = 0; v < 4; v++) {
            const int4 q4 = qp[v];
            const int qs[4] = {q4.x, q4.y, q4.z, q4.w};
            #pragma unroll
            for (int j = 0; j < 4; j++) {
                f16 t = (f16)qs[j];
                t = t * (f16)(2.0f / 15.0f);           // f16 mul (matches ref)
                t = t - (f16)1.0f;                     // f16 sub
                const f16 w = (f16)((float)t * s);     // f32 scale mul, round once
                if (v < 2) w0[v * 4 + j] = w; else w1[(v - 2) * 4 + j] = w;
            }
        }
        *(f16x8*)(Wdq + (size_t)g * 16) = w0;
        *(f16x8*)(Wdq + (size_t)g * 16 + 8) = w1;
    } else if (bid < 4320) {
        const int i = (bid - 3840) * 1024 + tid * 4;
        const float4 a = *(const float4*)(lA + i);
        f16x4 o = {(f16)a.x, (f16)a.y, (f16)a.z, (f16)a.w};
        *(f16x4*)(A16 + i) = o;
    } else if (bid < 4800) {
        const int i = (bid - 4320) * 1024 + tid * 4;
        const float4 a = *(const float4*)(lB + i);
        f16x4 o = {(f16)(0.125f * a.x), (f16)(0.125f * a.y),
                   (f16)(0.125f * a.z), (f16)(0.125f * a.w)};
        *(f16x4*)(B16 + i) = o;
    } else if (bid < 12992) {
        const int i = (bid - 4800) * 1024 + tid * 4;
        const float4 a = *(const float4*)(x + i);
        f16x4 o = {(f16)a.x, (f16)a.y, (f16)a.z, (f16)a.w};
        *(f16x4*)(x16 + i) = o;
    } else {
        const int md = *modep;
        const int i = (bid - 12992) * 1024 + tid * 4;
        float4 o;
        o.x = load_half_like(biases, i, md);
        o.y = load_half_like(biases, i + 1, md);
        o.z = load_half_like(biases, i + 2, md);
        o.w = load_half_like(biases, i + 3, md);
        *(float4*)(bias32 + i) = o;
    }
}

// ---------------------------------------------------------------------------
// Fused QLoRA layer: C = (X16 @ W^T) + bias + 0.125*(X16@A^T)@B^T  (f32 accum)
// then optional relu / residual-add; writes f16 and/or f32.
// 128x128 tile, BK=64, 256 thr (4 waves 2x2), mfma_f32_16x16x32_f16.
// LoRA stage-1 (T = X@A^T, rank 32) fused into the K loop (+25% MFMA).
// grid = 512 (64 row-blocks x 8 col-blocks).
// ---------------------------------------------------------------------------
__global__ __launch_bounds__(256, 2)
void layer_kernel(const f16* __restrict__ X16, const f16* __restrict__ W,
                  const f16* __restrict__ AL, const f16* __restrict__ BL,
                  const float* __restrict__ biasL, const float* __restrict__ resid,
                  float* __restrict__ out32, f16* __restrict__ out16, int do_relu)
{
    __shared__ __align__(16) f16 lds[18432];   // sA 16KB | sB 16KB | sL 4KB
    f16* sA = lds;                // [128][64]
    f16* sB = lds + 8192;         // [128][64]  (W rows = output cols)
    f16* sL = lds + 16384;        // [32][64]   (lora A)

    const int tid  = threadIdx.x;
    const int lane = tid & 63;
    const int wv   = tid >> 6;          // wave 0..3
    const int wy   = wv >> 1, wx = wv & 1;
    const int bx   = blockIdx.x & 7;    // col block
    const int by   = blockIdx.x >> 3;   // row block
    const int row0 = by << 7;
    const int col0 = bx << 7;

    const int lr = lane >> 3;           // staging: row-within-8
    const int lk = (lane & 7) << 3;     // staging: k elem offset
    const int m15 = lane & 15;
    const int q8  = (lane >> 4) << 3;

    f32x4 acc[4][4] = {};
    f32x4 tacc[2][2] = {};

    for (int kt = 0; kt < 16; kt++) {
        const int kb = kt << 6;
        if (kt) __syncthreads();
        #pragma unroll
        for (int i = 0; i < 4; i++) {
            const f16* gA = X16 + (size_t)(row0 + wv * 32 + i * 8 + lr) * 1024 + kb + lk;
            GLDS(gA, sA + (wv * 32 + i * 8) * 64);
            const f16* gB = W + (size_t)(col0 + wv * 32 + i * 8 + lr) * 1024 + kb + lk;
            GLDS(gB, sB + (wv * 32 + i * 8) * 64);
        }
        {
            const f16* gL = AL + (size_t)(wv * 8 + lr) * 1024 + kb + lk;
            GLDS(gL, sL + (wv * 8) * 64);
        }
        __syncthreads();   // compiler drains vmcnt(0) before s_barrier

        #pragma unroll
        for (int s = 0; s < 2; s++) {
            const int kk = s * 32 + q8;
            f16x8 af[4], bf[4], lf[2];
            #pragma unroll
            for (int mi = 0; mi < 4; mi++)
                af[mi] = *(const f16x8*)(sA + (wy * 64 + mi * 16 + m15) * 64 + kk);
            #pragma unroll
            for (int ni = 0; ni < 4; ni++)
                bf[ni] = *(const f16x8*)(sB + (wx * 64 + ni * 16 + m15) * 64 + kk);
            #pragma unroll
            for (int pi = 0; pi < 2; pi++)
                lf[pi] = *(const f16x8*)(sL + (pi * 16 + m15) * 64 + kk);
            #pragma unroll
            for (int mi = 0; mi < 4; mi++)
                #pragma unroll
                for (int ni = 0; ni < 4; ni++)
                    acc[mi][ni] = __builtin_amdgcn_mfma_f32_16x16x32_f16(af[mi], bf[ni], acc[mi][ni], 0, 0, 0);
            // lora stage-1: each wave covers its own 32 rows (m-frags 2wx, 2wx+1)
            #pragma unroll
            for (int mi = 0; mi < 2; mi++)
                #pragma unroll
                for (int pi = 0; pi < 2; pi++)
                    tacc[mi][pi] = __builtin_amdgcn_mfma_f32_16x16x32_f16(af[2 * wx + mi], lf[pi], tacc[mi][pi], 0, 0, 0);
        }
    }

    // ---- epilogue ----
    __syncthreads();
    float* Tl = (float*)lds;   // [128][32] f32, aliases sA (16KB)
    {
        const int q4 = (lane >> 4) << 2;
        #pragma unroll
        for (int mi = 0; mi < 2; mi++)
            #pragma unroll
            for (int pi = 0; pi < 2; pi++)
                #pragma unroll
                for (int r = 0; r < 4; r++)
                    Tl[(wy * 64 + wx * 32 + mi * 16 + q4 + r) * 32 + pi * 16 + m15] = tacc[mi][pi][r];
    }
    __syncthreads();

    f16x8 tf[4];    // T in A-fragment layout (k = lora dim, K=32 -> one k-step)
    #pragma unroll
    for (int mi = 0; mi < 4; mi++) {
        const float* tp = Tl + (wy * 64 + mi * 16 + m15) * 32 + q8;
        f16x8 v;
        #pragma unroll
        for (int j = 0; j < 8; j++) v[j] = (f16)tp[j];
        tf[mi] = v;
    }
    f16x8 bfr[4]; float bb[4];
    #pragma unroll
    for (int ni = 0; ni < 4; ni++) {
        const int colg = col0 + wx * 64 + ni * 16 + m15;
        bfr[ni] = *(const f16x8*)(BL + (size_t)colg * 32 + q8);  // pre-scaled 0.125
        bb[ni] = biasL[colg];
    }
    #pragma unroll
    for (int mi = 0; mi < 4; mi++)
        #pragma unroll
        for (int ni = 0; ni < 4; ni++) {
            #pragma unroll
            for (int r = 0; r < 4; r++)
                acc[mi][ni][r] += bb[ni];      // f32 bias add (ref promotes to f32)
            acc[mi][ni] = __builtin_amdgcn_mfma_f32_16x16x32_f16(tf[mi], bfr[ni], acc[mi][ni], 0, 0, 0);
        }

    const int q4 = (lane >> 4) << 2;
    #pragma unroll
    for (int mi = 0; mi < 4; mi++)
        #pragma unroll
        for (int ni = 0; ni < 4; ni++) {
            const int colg = col0 + wx * 64 + ni * 16 + m15;
            const int rowb = row0 + wy * 64 + mi * 16 + q4;
            #pragma unroll
            for (int r = 0; r < 4; r++) {
                float v = acc[mi][ni][r];
                const int idx = (rowb + r) * 1024 + colg;
                if (resid) v += resid[idx];
                if (do_relu) v = fmaxf(v, 0.0f);
                if (out32) out32[idx] = v;
                if (out16) out16[idx] = (f16)v;
            }
        }
}

// ---------------------------------------------------------------------------
// LayerNorm over rows of h (f32, in place) + f16 copy for next GEMM input.
// grid = 8192 rows, block = 256 (4 f32 per thread).
// ---------------------------------------------------------------------------
__global__ void ln_kernel(float* __restrict__ h, f16* __restrict__ h16,
                          const float* __restrict__ g, const float* __restrict__ b)
{
    const int row = blockIdx.x, tid = threadIdx.x;
    float* hp = h + (size_t)row * 1024;
    const int c = tid * 4;
    const float4 v = *(const float4*)(hp + c);
    float s = v.x + v.y + v.z + v.w;
    #pragma unroll
    for (int off = 32; off > 0; off >>= 1) s += __shfl_down(s, off);
    __shared__ float r1[4], r2[4];
    const int wv = tid >> 6, lane = tid & 63;
    if (lane == 0) r1[wv] = s;
    __syncthreads();
    const float mu = (r1[0] + r1[1] + r1[2] + r1[3]) * (1.0f / 1024.0f);
    const float dx = v.x - mu, dy = v.y - mu, dz = v.z - mu, dw = v.w - mu;
    float s2 = dx * dx + dy * dy + dz * dz + dw * dw;
    #pragma unroll
    for (int off = 32; off > 0; off >>= 1) s2 += __shfl_down(s2, off);
    if (lane == 0) r2[wv] = s2;
    __syncthreads();
    const float var = (r2[0] + r2[1] + r2[2] + r2[3]) * (1.0f / 1024.0f);
    const float rs = 1.0f / sqrtf(var + 1e-5f);
    float4 o;
    o.x = dx * rs * g[c]     + b[c];
    o.y = dy * rs * g[c + 1] + b[c + 1];
    o.z = dz * rs * g[c + 2] + b[c + 2];
    o.w = dw * rs * g[c + 3] + b[c + 3];
    *(float4*)(hp + c) = o;
    f16x4 o16 = {(f16)o.x, (f16)o.y, (f16)o.z, (f16)o.w};
    *(f16x4*)(h16 + (size_t)row * 1024 + c) = o16;
}

// ---------------------------------------------------------------------------
// ws layout (~64 MB): mode@0 | bias32@64 | Wdq@65536 | A16 | B16 | fA | fB
// f32 residual carrier lives in d_out (overwritten fully every call).
// ---------------------------------------------------------------------------
extern "C" void kernel_launch(void* const* d_in, const int* in_sizes, int n_in,
                              void* d_out, int out_size, void* d_ws, size_t ws_size,
                              hipStream_t stream)
{
    const float* x      = (const float*)d_in[0];
    const int*   qw     = (const int*)d_in[1];
    const void*  scales = d_in[2];
    const void*  biases = d_in[3];
    const float* lA     = (const float*)d_in[4];
    const float* lB     = (const float*)d_in[5];
    const float* lng    = (const float*)d_in[6];
    const float* lnb    = (const float*)d_in[7];
    float* out = (float*)d_out;

    char* ws = (char*)d_ws;
    int*   mode   = (int*)(ws);
    float* bias32 = (float*)(ws + 64);
    f16* Wdq = (f16*)(ws + 65536u);
    f16* A16 = (f16*)(ws + 31522816u);
    f16* B16 = (f16*)(ws + 32505856u);
    f16* fA  = (f16*)(ws + 33488896u);
    f16* fB  = (f16*)(ws + 50266112u);
    float* h32 = out;   // residual carrier in d_out

    detect_kernel<<<1, 64, 0, stream>>>((const unsigned short*)scales, mode);
    prep_kernel<<<13007, 256, 0, stream>>>(x, qw, scales, biases, lA, lB, mode,
                                           Wdq, A16, B16, fA, bias32);

    int li = 0;
    for (int blk = 0; blk < 6; blk++) {
        const float* resid = (blk == 0) ? x : h32;
        for (int j = 0; j < 3; j++, li++) {
            const int wl = li < 15 ? li : 14;      // JAX clamps q_w[15..17] -> 14
            const f16* in16 = (j == 1) ? fB : fA;
            f16* o16 = (j == 0) ? fB : (j == 1 ? fA : (f16*)nullptr);
            float* o32 = nullptr;
            const float* rz = nullptr;
            if (j == 2) { o32 = h32; rz = resid; }
            layer_kernel<<<512, 256, 0, stream>>>(in16,
                Wdq + (size_t)wl * 1048576,
                A16 + (size_t)wl * 32768,
                B16 + (size_t)wl * 32768,
                bias32 + (size_t)wl * 1024,
                rz, o32, o16, j < 2 ? 1 : 0);
        }
        if (blk < 5)
            ln_kernel<<<8192, 256, 0, stream>>>(h32, fA, lng + blk * 1024, lnb + blk * 1024);
    }
}